// Round 1
// baseline (193.430 us; speedup 1.0000x reference)
//
#include <hip/hip_runtime.h>
#include <hip/hip_bf16.h>

// LinearAttention_MLP on MI355X — round 6 (round 5 + pipelined main_gemm).
// Math: k-softmax over size-1 axis == 1 -> s = 0.125 exactly -> out = 0.125*v.
// Fold: y = x @ Weff^T, Weff = 0.125*Wo@Wv (1024x1024).
// Pipeline (3 launches):
//   weff_fused : Weff = bf16(0.125*Wo@Wv) fp32 in, 64x64 tiles, 256 blocks
//   main_gemm  : y_bf = bf16(x@Weff^T + b). NEW: double-buffered LDS, one
//                raw s_barrier per K-step with COUNTED s_waitcnt vmcnt(8)
//                (T3/T4 minimum-2-phase). B via global_load_lds stays in
//                flight under the MFMAs; A reg-prefetch is 2 tiles deep.
//   rmsnorm2   : out = y/max(||y||,eps)*g*32  (fp32)
//
// Swizzle convention (round-3 validated):
//   STORE: LDS chunk c holds GLOBAL chunk c ^ s   (s = row&7; swizzle global k)
//   READ : to get global chunk q, read LDS chunk q ^ s
//
// vmcnt accounting per iter (issue order pinned by sched_barrier(0)):
//   [4x global_load_lds B(t+1)] < fence < [8x global_load A(t+2)] < asm
//   -> s_waitcnt vmcnt(8) drains exactly the 4 B loads, keeps A in flight.
//   Last staging iter (t==14) issues no A loads -> vmcnt(0) there.

typedef __attribute__((ext_vector_type(8))) short bf16x8;
typedef __attribute__((ext_vector_type(4))) float f32x4;

struct alignas(16) bfvec8 { __hip_bfloat16 h[8]; };

__device__ __forceinline__ bfvec8 pack8(float4 a, float4 b) {
    bfvec8 o;
    o.h[0] = __float2bfloat16(a.x); o.h[1] = __float2bfloat16(a.y);
    o.h[2] = __float2bfloat16(a.z); o.h[3] = __float2bfloat16(a.w);
    o.h[4] = __float2bfloat16(b.x); o.h[5] = __float2bfloat16(b.y);
    o.h[6] = __float2bfloat16(b.z); o.h[7] = __float2bfloat16(b.w);
    return o;
}

// ---------------- weff_fused: Weff = 0.125 * Wo @ Wv, fp32 in, bf16 out ----------------
// Wo: (1024,512) row-major. Wv: (512,1024) row-major (transposed in LDS).
// 64x64 tiles, BK=32, grid 16x16 = 256 blocks (all CUs busy).
__global__ __launch_bounds__(256)
void weff_fused(const float* __restrict__ Wo, const float* __restrict__ Wv,
                __hip_bfloat16* __restrict__ Weff) {
    __shared__ __align__(16) __hip_bfloat16 As[64 * 32];
    __shared__ __align__(16) __hip_bfloat16 Bs[64 * 32];
    __shared__ __align__(16) float Bf[32 * 65];   // fp32 transpose staging, stride 65

    const int tid  = threadIdx.x;
    const int lane = tid & 63;
    const int wave = tid >> 6;
    const int wm   = wave >> 1;
    const int wn   = wave & 1;
    const int quad = lane >> 4;
    const int tr   = lane & 15;
    const int m0   = blockIdx.y * 64;
    const int n0   = blockIdx.x * 64;

    f32x4 acc[2][2];
#pragma unroll
    for (int i = 0; i < 2; ++i)
#pragma unroll
        for (int j = 0; j < 2; ++j)
            acc[i][j] = (f32x4){0.f, 0.f, 0.f, 0.f};

    for (int kt = 0; kt < 512; kt += 32) {
        // A: 64x32 fp32 -> cvt -> As. LDS chunk c holds global chunk c ^ s.
        {
            int r = tid >> 2, c = tid & 3;
            int s = (r >> 1) & 3;
            int kg = (c ^ s) << 3;                 // global chunk for LDS chunk c
            const float* sp = Wo + (size_t)(m0 + r) * 512 + kt + kg;
            float4 a = *(const float4*)sp, b = *(const float4*)(sp + 4);
            *(bfvec8*)(As + r * 32 + (c << 3)) = pack8(a, b);   // un-swizzled LDS addr
        }
        // B fp32 (coalesced rows of Wv) -> Bf
        {
            int kr = tid >> 3, c8 = (tid & 7) << 3;
            const float* sp = Wv + (size_t)(kt + kr) * 1024 + n0 + c8;
            float4 a = *(const float4*)sp, b = *(const float4*)(sp + 4);
            *(float4*)(Bf + kr * 65 + c8)     = a;
            *(float4*)(Bf + kr * 65 + c8 + 4) = b;
        }
        __syncthreads();
        // transpose + cvt: LDS chunk (cc ^ s) holds global chunk cc
        {
            int n = tid >> 2, cc = tid & 3, k8 = cc << 3;
            float4 a, b;
            a.x = Bf[(k8 + 0) * 65 + n]; a.y = Bf[(k8 + 1) * 65 + n];
            a.z = Bf[(k8 + 2) * 65 + n]; a.w = Bf[(k8 + 3) * 65 + n];
            b.x = Bf[(k8 + 4) * 65 + n]; b.y = Bf[(k8 + 5) * 65 + n];
            b.z = Bf[(k8 + 6) * 65 + n]; b.w = Bf[(k8 + 7) * 65 + n];
            int cs = cc ^ ((n >> 1) & 3);
            *(bfvec8*)(Bs + n * 32 + cs * 8) = pack8(a, b);
        }
        __syncthreads();

        bf16x8 af[2], bf[2];
#pragma unroll
        for (int mi = 0; mi < 2; ++mi) {
            int r = wm * 32 + mi * 16 + tr;
            int c = quad ^ ((r >> 1) & 3);         // LDS chunk holding global chunk quad
            af[mi] = *(const bf16x8*)(As + r * 32 + c * 8);
        }
#pragma unroll
        for (int ni = 0; ni < 2; ++ni) {
            int r = wn * 32 + ni * 16 + tr;
            int c = quad ^ ((r >> 1) & 3);
            bf[ni] = *(const bf16x8*)(Bs + r * 32 + c * 8);
        }
#pragma unroll
        for (int mi = 0; mi < 2; ++mi)
#pragma unroll
            for (int ni = 0; ni < 2; ++ni)
                acc[mi][ni] = __builtin_amdgcn_mfma_f32_16x16x32_bf16(
                    af[mi], bf[ni], acc[mi][ni], 0, 0, 0);
        __syncthreads();
    }

#pragma unroll
    for (int mi = 0; mi < 2; ++mi)
#pragma unroll
        for (int ni = 0; ni < 2; ++ni) {
            const int col = n0 + wn * 32 + ni * 16 + tr;
#pragma unroll
            for (int r = 0; r < 4; ++r) {
                const int row = m0 + wm * 32 + mi * 16 + quad * 4 + r;
                Weff[(size_t)row * 1024 + col] =
                    __float2bfloat16(acc[mi][ni][r] * 0.125f);
            }
        }
}

// ---------------- main GEMM: y = x @ Weff^T + b ----------------
// M=16384, N=1024, K=1024, BLK=128, BK=64. 1D grid of 1024 blocks.
// Double-buffered LDS (64 KiB), one s_barrier per K-step, counted vmcnt.

__device__ __forceinline__ void mfma_tile(const __hip_bfloat16* Ac,
                                          const __hip_bfloat16* Bc,
                                          f32x4 (&acc)[4][4],
                                          int wm, int wn, int quad, int tr) {
#pragma unroll
    for (int ko = 0; ko < 2; ++ko) {
        bf16x8 af[4], bf[4];
#pragma unroll
        for (int mi = 0; mi < 4; ++mi) {
            int r = wm * 64 + mi * 16 + tr;
            int c = (ko * 4 + quad) ^ (r & 7);     // LDS chunk holding global chunk
            af[mi] = *(const bf16x8*)(Ac + (r * 8 + c) * 8);
        }
#pragma unroll
        for (int ni = 0; ni < 4; ++ni) {
            int r = wn * 64 + ni * 16 + tr;
            int c = (ko * 4 + quad) ^ (r & 7);
            bf[ni] = *(const bf16x8*)(Bc + (r * 8 + c) * 8);
        }
#pragma unroll
        for (int mi = 0; mi < 4; ++mi)
#pragma unroll
            for (int ni = 0; ni < 4; ++ni)
                acc[mi][ni] = __builtin_amdgcn_mfma_f32_16x16x32_bf16(
                    af[mi], bf[ni], acc[mi][ni], 0, 0, 0);
    }
}

__global__ __launch_bounds__(256)
void main_gemm(const float* __restrict__ X,
               const __hip_bfloat16* __restrict__ Bt,
               const float* __restrict__ bias,
               __hip_bfloat16* __restrict__ Y) {
    __shared__ __align__(16) __hip_bfloat16 As[2 * 128 * 64];
    __shared__ __align__(16) __hip_bfloat16 Bs[2 * 128 * 64];

    const int tid  = threadIdx.x;
    const int lane = tid & 63;
    const int wave = tid >> 6;
    const int wm   = wave >> 1;
    const int wn   = wave & 1;
    const int quad = lane >> 4;
    const int tr   = lane & 15;

    // XCD-aware mapping: all 8 n-tiles of an m-strip on one XCD (A fetched once)
    const int b   = blockIdx.x;
    const int xcd = b & 7;
    const int tb  = b >> 3;
    const int ntl = tb & 7;
    const int mtl = (tb >> 3) * 8 + xcd;
    const int m0  = mtl * 128;
    const int n0  = ntl * 128;

    // Per-slot constants for the 4 staging slots this thread owns.
    // Slot L: LDS chunk c = L&7 holds global chunk c ^ (r&7).
    int rr[4], kgg[4], ldst[4];
    size_t abase[4];
    const __hip_bfloat16* bbase[4];
#pragma unroll
    for (int i = 0; i < 4; ++i) {
        int L = i * 256 + tid;            // 0..1023
        rr[i]   = L >> 3;                 // tile row 0..127
        int c   = L & 7;                  // LDS chunk
        kgg[i]  = (c ^ (rr[i] & 7)) << 3; // swizzled global k-offset (elements)
        ldst[i] = L * 8;                  // LDS element offset (un-swizzled)
        abase[i] = (size_t)(m0 + rr[i]) * 1024 + kgg[i];
        bbase[i] = Bt + (size_t)(n0 + rr[i]) * 1024 + kgg[i];
    }

    f32x4 acc[4][4];
#pragma unroll
    for (int i = 0; i < 4; ++i)
#pragma unroll
        for (int j = 0; j < 4; ++j)
            acc[i][j] = (f32x4){0.f, 0.f, 0.f, 0.f};

    __hip_bfloat16* Ac = As;
    __hip_bfloat16* An = As + 128 * 64;
    __hip_bfloat16* Bc = Bs;
    __hip_bfloat16* Bn = Bs + 128 * 64;

    // ---- Prologue: stage tile 0 fully, then start A-prefetch of tile 1 ----
    float4 pa[4], pb[4];
#pragma unroll
    for (int i = 0; i < 4; ++i) {
        const float* s = X + abase[i];
        pa[i] = *(const float4*)s;
        pb[i] = *(const float4*)(s + 4);
    }
#pragma unroll
    for (int i = 0; i < 4; ++i)
        __builtin_amdgcn_global_load_lds(
            (const __attribute__((address_space(1))) void*)(bbase[i]),
            (__attribute__((address_space(3))) void*)(Bc + ldst[i]), 16, 0, 0);
#pragma unroll
    for (int i = 0; i < 4; ++i)
        *(bfvec8*)(Ac + ldst[i]) = pack8(pa[i], pb[i]);
    __syncthreads();                       // full drain once (prologue only)
#pragma unroll
    for (int i = 0; i < 4; ++i) {          // A tile 1 -> regs, in flight
        const float* s = X + abase[i] + 64;
        pa[i] = *(const float4*)s;
        pb[i] = *(const float4*)(s + 4);
    }

    // ---- Main loop: 15 staging iterations + 1 compute-only ----
    for (int t = 0; t < 15; ++t) {
        const int koff = (t + 1) * 64;

        // Issue B loads for tile t+1 into the other buffer (stay in flight).
#pragma unroll
        for (int i = 0; i < 4; ++i)
            __builtin_amdgcn_global_load_lds(
                (const __attribute__((address_space(1))) void*)(bbase[i] + koff),
                (__attribute__((address_space(3))) void*)(Bn + ldst[i]), 16, 0, 0);
        // Fence: pin VMEM issue order (B-lds before later A reg loads) so the
        // hand-counted vmcnt below is FIFO-correct.
        __builtin_amdgcn_sched_barrier(0);

        // Compute tile t while B(t+1) flies.
        mfma_tile(Ac, Bc, acc, wm, wn, quad, tr);

        // Stage A(t+1) from regs (compiler inserts counted vmcnt wait on pa).
#pragma unroll
        for (int i = 0; i < 4; ++i)
            *(bfvec8*)(An + ldst[i]) = pack8(pa[i], pb[i]);

        if (t < 14) {
            // A tile t+2 -> regs (8 loads, newest; stay in flight over barrier)
#pragma unroll
            for (int i = 0; i < 4; ++i) {
                const float* s = X + abase[i] + koff + 64;
                pa[i] = *(const float4*)s;
                pb[i] = *(const float4*)(s + 4);
            }
            // Drain the 4 B-lds (oldest), keep the 8 A loads outstanding.
            asm volatile("s_waitcnt vmcnt(8) lgkmcnt(0)" ::: "memory");
        } else {
            // Last staging iter: nothing newer issued -> full drain.
            asm volatile("s_waitcnt vmcnt(0) lgkmcnt(0)" ::: "memory");
        }
        __builtin_amdgcn_sched_barrier(0);
        __builtin_amdgcn_s_barrier();

        // Swap buffers.
        __hip_bfloat16* tA = Ac; Ac = An; An = tA;
        __hip_bfloat16* tB = Bc; Bc = Bn; Bn = tB;
    }
    // Final tile (15): buffers already staged, no prefetch.
    mfma_tile(Ac, Bc, acc, wm, wn, quad, tr);

    // Epilogue: C/D layout col = lane&15, row = quad*4 + reg.
#pragma unroll
    for (int mi = 0; mi < 4; ++mi)
#pragma unroll
        for (int ni = 0; ni < 4; ++ni) {
            const int col = n0 + wn * 64 + ni * 16 + tr;
            const float bv = bias[col];
#pragma unroll
            for (int r = 0; r < 4; ++r) {
                const int row = m0 + wm * 64 + mi * 16 + quad * 4 + r;
                Y[(size_t)row * 1024 + col] = __float2bfloat16(acc[mi][ni][r] + bv);
            }
        }
}

// ---------------- norm: out = y / max(||y||,eps) * g * 32, 2 rows/block ----------------
__global__ __launch_bounds__(256)
void rmsnorm2(const __hip_bfloat16* __restrict__ y, const float* __restrict__ g,
              float* __restrict__ out) {
    const int wave = threadIdx.x >> 6;     // 0..3
    const int sub  = wave >> 1;            // which of 2 rows
    const int t    = threadIdx.x & 127;    // 0..127 within row
    const int row  = blockIdx.x * 2 + sub;
    const size_t base = (size_t)row * 1024 + t * 8;

    union { uint4 u; ushort s[8]; } U;
    U.u = *(const uint4*)(y + base);
    float v[8];
#pragma unroll
    for (int j = 0; j < 8; ++j)
        v[j] = __bfloat162float(*(const __hip_bfloat16*)&U.s[j]);

    float ss = 0.f;
#pragma unroll
    for (int j = 0; j < 8; ++j) ss += v[j] * v[j];
#pragma unroll
    for (int off = 32; off > 0; off >>= 1)
        ss += __shfl_down(ss, off, 64);

    __shared__ float wsum[4];
    if ((threadIdx.x & 63) == 0) wsum[wave] = ss;
    __syncthreads();
    const float total = wsum[sub * 2] + wsum[sub * 2 + 1];
    const float sc = 32.0f / fmaxf(sqrtf(total), 1e-12f);

    const float4 g0 = *(const float4*)(g + t * 8);
    const float4 g1 = *(const float4*)(g + t * 8 + 4);
    float4 o0, o1;
    o0.x = v[0] * sc * g0.x; o0.y = v[1] * sc * g0.y;
    o0.z = v[2] * sc * g0.z; o0.w = v[3] * sc * g0.w;
    o1.x = v[4] * sc * g1.x; o1.y = v[5] * sc * g1.y;
    o1.z = v[6] * sc * g1.z; o1.w = v[7] * sc * g1.w;
    *(float4*)(out + base)     = o0;
    *(float4*)(out + base + 4) = o1;
}

extern "C" void kernel_launch(void* const* d_in, const int* in_sizes, int n_in,
                              void* d_out, int out_size, void* d_ws, size_t ws_size,
                              hipStream_t stream) {
    const float* x     = (const float*)d_in[0];   // (16384, 1024)
    const float* w_qkv = (const float*)d_in[1];   // (1536, 1024)
    const float* w_out = (const float*)d_in[2];   // (1024, 512)
    const float* b_out = (const float*)d_in[3];   // (1024,)
    const float* g     = (const float*)d_in[4];   // (1, 1024)

    const int B = 16384, D = 1024, H = 512;
    const float* wv = w_qkv + (size_t)2 * H * D;  // v-rows: (512, 1024)

    char* ws = (char*)d_ws;
    size_t off = 0;
    __hip_bfloat16* weff_bf = (__hip_bfloat16*)(ws + off); off += (size_t)D * D * 2;  // 2 MB
    __hip_bfloat16* y_bf    = (__hip_bfloat16*)(ws + off); off += (size_t)B * D * 2;  // 32 MB

    weff_fused<<<dim3(D / 64, D / 64), 256, 0, stream>>>(w_out, wv, weff_bf);
    main_gemm<<<1024, 256, 0, stream>>>(x, weff_bf, b_out, y_bf);
    rmsnorm2<<<B / 2, 256, 0, stream>>>(y_bf, g, (float*)d_out);
}

// Round 2
// 178.416 us; speedup vs baseline: 1.0841x; 1.0841x over previous
//
#include <hip/hip_runtime.h>
#include <hip/hip_bf16.h>

// LinearAttention_MLP on MI355X — round 7: 256x256 8-phase main GEMM (T3+T4+T5).
// Math: k-softmax over size-1 axis == 1 -> s = 0.125 exactly -> out = 0.125*v.
// Fold: y = x @ Weff^T, Weff = 0.125*Wo@Wv (1024x1024).
// Pipeline (3 launches):
//   prep       : [blocks 0..255]   Weff = bf16(0.125*Wo@Wv)  (round-5 weff, unchanged)
//                [blocks 256..2303] Xbf = bf16(X)  (grid-stride, overlapped with weff)
//   main_gemm  : y_bf = bf16(Xbf@Weff^T + b). 256x256 tile, BK=64, 512 thr (8 waves),
//                per-wave 256x32, 4 phases/K-tile, dbuf LDS 128KB, counted vmcnt(6),
//                setprio around MFMA. Schedule (derived + race-checked):
//                  tile u phase0: stage (u+1).A1 -> other buf   [B reads this phase only]
//                  tile u phase1: stage (u+2).B0 -> read buf    [B reads done at p0]
//                  tile u phase2: stage (u+2).B1 -> read buf
//                  tile u phase3: stage (u+2).A0 -> read buf    [A0 reads done at p1]
//                  boundary: vmcnt(6)=3 halves in flight; completes ALL of tile u+1.
//   rmsnorm2   : out = y/max(||y||,eps)*g*32  (fp32, unchanged)
//
// Swizzle convention (round-3/5 validated, 0 bank conflicts):
//   STORE: LDS chunk c holds GLOBAL chunk c ^ (r&7)  (swizzle the global k only)
//   READ : global chunk q lives in LDS chunk q ^ (r&7)
//
// WORKSPACE: needs 2MB (Weff) + 33.6MB (y_bf) + 33.6MB (Xbf) = ~69.2 MB.

typedef __attribute__((ext_vector_type(8))) short bf16x8;
typedef __attribute__((ext_vector_type(4))) float f32x4;

struct alignas(16) bfvec8 { __hip_bfloat16 h[8]; };

__device__ __forceinline__ bfvec8 pack8(float4 a, float4 b) {
    bfvec8 o;
    o.h[0] = __float2bfloat16(a.x); o.h[1] = __float2bfloat16(a.y);
    o.h[2] = __float2bfloat16(a.z); o.h[3] = __float2bfloat16(a.w);
    o.h[4] = __float2bfloat16(b.x); o.h[5] = __float2bfloat16(b.y);
    o.h[6] = __float2bfloat16(b.z); o.h[7] = __float2bfloat16(b.w);
    return o;
}

// ---------------- prep: weff (blocks 0..255) + X->bf16 cvt (blocks 256..2303) ----------
__global__ __launch_bounds__(256)
void prep(const float* __restrict__ Wo, const float* __restrict__ Wv,
          __hip_bfloat16* __restrict__ Weff,
          const float* __restrict__ X, __hip_bfloat16* __restrict__ Xbf) {
    __shared__ __align__(16) __hip_bfloat16 As[64 * 32];
    __shared__ __align__(16) __hip_bfloat16 Bs[64 * 32];
    __shared__ __align__(16) float Bf[32 * 65];

    const int tid = threadIdx.x;

    if (blockIdx.x >= 256) {
        // ---- X (16384x1024 fp32) -> Xbf bf16, vectorized grid-stride ----
        const size_t nv = (size_t)16384 * 1024 / 8;          // 2,097,152 vec8
        const size_t stride = (size_t)2048 * 256;
        for (size_t i = (size_t)(blockIdx.x - 256) * 256 + tid; i < nv; i += stride) {
            const float4 a = *(const float4*)(X + i * 8);
            const float4 b = *(const float4*)(X + i * 8 + 4);
            *(bfvec8*)(Xbf + i * 8) = pack8(a, b);
        }
        return;
    }

    // ---- weff body (round-5, validated): Weff = 0.125 * Wo @ Wv ----
    const int lane = tid & 63;
    const int wave = tid >> 6;
    const int wm   = wave >> 1;
    const int wn   = wave & 1;
    const int quad = lane >> 4;
    const int tr   = lane & 15;
    const int m0   = (blockIdx.x >> 4) * 64;
    const int n0   = (blockIdx.x & 15) * 64;

    f32x4 acc[2][2];
#pragma unroll
    for (int i = 0; i < 2; ++i)
#pragma unroll
        for (int j = 0; j < 2; ++j)
            acc[i][j] = (f32x4){0.f, 0.f, 0.f, 0.f};

    for (int kt = 0; kt < 512; kt += 32) {
        {
            int r = tid >> 2, c = tid & 3;
            int s = (r >> 1) & 3;
            int kg = (c ^ s) << 3;
            const float* sp = Wo + (size_t)(m0 + r) * 512 + kt + kg;
            float4 a = *(const float4*)sp, b = *(const float4*)(sp + 4);
            *(bfvec8*)(As + r * 32 + (c << 3)) = pack8(a, b);
        }
        {
            int kr = tid >> 3, c8 = (tid & 7) << 3;
            const float* sp = Wv + (size_t)(kt + kr) * 1024 + n0 + c8;
            float4 a = *(const float4*)sp, b = *(const float4*)(sp + 4);
            *(float4*)(Bf + kr * 65 + c8)     = a;
            *(float4*)(Bf + kr * 65 + c8 + 4) = b;
        }
        __syncthreads();
        {
            int n = tid >> 2, cc = tid & 3, k8 = cc << 3;
            float4 a, b;
            a.x = Bf[(k8 + 0) * 65 + n]; a.y = Bf[(k8 + 1) * 65 + n];
            a.z = Bf[(k8 + 2) * 65 + n]; a.w = Bf[(k8 + 3) * 65 + n];
            b.x = Bf[(k8 + 4) * 65 + n]; b.y = Bf[(k8 + 5) * 65 + n];
            b.z = Bf[(k8 + 6) * 65 + n]; b.w = Bf[(k8 + 7) * 65 + n];
            int cs = cc ^ ((n >> 1) & 3);
            *(bfvec8*)(Bs + n * 32 + cs * 8) = pack8(a, b);
        }
        __syncthreads();

        bf16x8 af[2], bfr[2];
#pragma unroll
        for (int mi = 0; mi < 2; ++mi) {
            int r = wm * 32 + mi * 16 + tr;
            int c = quad ^ ((r >> 1) & 3);
            af[mi] = *(const bf16x8*)(As + r * 32 + c * 8);
        }
#pragma unroll
        for (int ni = 0; ni < 2; ++ni) {
            int r = wn * 32 + ni * 16 + tr;
            int c = quad ^ ((r >> 1) & 3);
            bfr[ni] = *(const bf16x8*)(Bs + r * 32 + c * 8);
        }
#pragma unroll
        for (int mi = 0; mi < 2; ++mi)
#pragma unroll
            for (int ni = 0; ni < 2; ++ni)
                acc[mi][ni] = __builtin_amdgcn_mfma_f32_16x16x32_bf16(
                    af[mi], bfr[ni], acc[mi][ni], 0, 0, 0);
        __syncthreads();
    }

#pragma unroll
    for (int mi = 0; mi < 2; ++mi)
#pragma unroll
        for (int ni = 0; ni < 2; ++ni) {
            const int col = n0 + wn * 32 + ni * 16 + tr;
#pragma unroll
            for (int r = 0; r < 4; ++r) {
                const int row = m0 + wm * 32 + mi * 16 + quad * 4 + r;
                Weff[(size_t)row * 1024 + col] =
                    __float2bfloat16(acc[mi][ni][r] * 0.125f);
            }
        }
}

// ---------------- main GEMM: y = Xbf @ Weff^T + b, 256x256 8-phase ----------------
// M=16384, N=1024, K=1024. Grid 256 blocks (64 m x 4 n), 512 threads (8 waves).
// LDS 128KB: buf b at b*32768 elems; A @ +0, B @ +16384; halves of 8192 elems.

#define GLL(gp, lp) __builtin_amdgcn_global_load_lds( \
    (const __attribute__((address_space(1))) void*)(gp), \
    (__attribute__((address_space(3))) void*)(lp), 16, 0, 0)

#define STAGE_A(BUF, H, U) do { \
    GLL(Xbf + Ab0 + (size_t)(H) * 131072 + (size_t)(U) * 64, \
        sm + (BUF) * 32768 + (H) * 8192 + ldsA);             \
    GLL(Xbf + Ab1 + (size_t)(H) * 131072 + (size_t)(U) * 64, \
        sm + (BUF) * 32768 + (H) * 8192 + 4096 + ldsA);      \
} while (0)

#define STAGE_B(BUF, H, U) do { \
    GLL(Bt + Bb0 + (size_t)(H) * 131072 + (size_t)(U) * 64,  \
        sm + (BUF) * 32768 + 16384 + (H) * 8192 + ldsA);     \
    GLL(Bt + Bb1 + (size_t)(H) * 131072 + (size_t)(U) * 64,  \
        sm + (BUF) * 32768 + 16384 + (H) * 8192 + 4096 + ldsA); \
} while (0)

__global__ __launch_bounds__(512, 2)
void main_gemm(const __hip_bfloat16* __restrict__ Xbf,
               const __hip_bfloat16* __restrict__ Bt,
               const float* __restrict__ bias,
               __hip_bfloat16* __restrict__ Y) {
    __shared__ __align__(16) __hip_bfloat16 sm[2 * 32768];   // 128 KiB

    const int tid  = threadIdx.x;          // 0..511
    const int lane = tid & 63;
    const int wc   = tid >> 6;             // wave = col group 0..7 (cols wc*32)
    const int quad = lane >> 4;
    const int tr   = lane & 15;
    const int rlow = tr & 7;

    // XCD-aware: 256 blocks; XCD x gets orig chunk [x*32, x*32+32) (8 m-strips x 4 n)
    const int xcd  = blockIdx.x & 7;
    const int orig = xcd * 32 + (blockIdx.x >> 3);
    const int m0   = (orig >> 2) * 256;
    const int n0   = (orig & 3) * 256;

    // Staging constants. Slot s in {tid, tid+512}: r=s>>3, c=s&7, kg=((c^(r&7))<<3).
    // LDS dest is linear (wave-uniform base + lane*16); global k is inverse-swizzled.
    const int r0 = tid >> 3,            c0 = tid & 7;
    const int r1 = (tid + 512) >> 3,    c1 = tid & 7;   // (tid+512)&7 == tid&7
    const size_t Ab0 = (size_t)(m0 + r0) * 1024 + ((c0 ^ (r0 & 7)) << 3);
    const size_t Ab1 = (size_t)(m0 + r1) * 1024 + ((c1 ^ (r1 & 7)) << 3);
    const size_t Bb0 = (size_t)(n0 + r0) * 1024 + ((c0 ^ (r0 & 7)) << 3);
    const size_t Bb1 = (size_t)(n0 + r1) * 1024 + ((c1 ^ (r1 & 7)) << 3);
    const int ldsA = tid * 8;                           // elems; slot1 adds 4096

    // Read chunk offsets per ko: global chunk q = ko*4+quad lives in LDS chunk q^rlow.
    int ac[2];
#pragma unroll
    for (int ko = 0; ko < 2; ++ko) ac[ko] = ((ko * 4 + quad) ^ rlow) * 8;
    const int rdA = tr * 64;                            // + p*4096 + mi*1024
    const int rdB = wc * 2048 + tr * 64;                // + ni*1024

    f32x4 acc[16][2];
#pragma unroll
    for (int f = 0; f < 16; ++f)
#pragma unroll
        for (int ni = 0; ni < 2; ++ni)
            acc[f][ni] = (f32x4){0.f, 0.f, 0.f, 0.f};

    // ---- Prologue: stage [0.B0 0.B1 0.A0 0.A1 1.B0 1.B1 1.A0] = 14 loads ----
    STAGE_B(0, 0, 0); STAGE_B(0, 1, 0); STAGE_A(0, 0, 0); STAGE_A(0, 1, 0);
    STAGE_B(1, 0, 1); STAGE_B(1, 1, 1); STAGE_A(1, 0, 1);
    asm volatile("s_waitcnt vmcnt(6)" ::: "memory");     // tile 0 complete, tile 1 flying
    __builtin_amdgcn_s_barrier();

    bf16x8 bfr[2][2];

    // ---- Main loop: 16 K-tiles, double-unrolled for static buffer bases ----
    for (int it = 0; it < 8; ++it) {
#pragma unroll
        for (int rb = 0; rb < 2; ++rb) {                 // rb = read buffer (compile-time)
            const int u = it * 2 + rb;                   // K-tile index (uniform)
#pragma unroll
            for (int p = 0; p < 4; ++p) {                // 4 phases per K-tile
                // ds-load register subtile for this phase (rows p*64..p*64+63)
                bf16x8 af[4][2];
#pragma unroll
                for (int mi = 0; mi < 4; ++mi)
#pragma unroll
                    for (int ko = 0; ko < 2; ++ko)
                        af[mi][ko] = *(const bf16x8*)(
                            sm + rb * 32768 + p * 4096 + mi * 1024 + rdA + ac[ko]);
                if (p == 0) {                            // B frags for whole K-tile
#pragma unroll
                    for (int ni = 0; ni < 2; ++ni)
#pragma unroll
                        for (int ko = 0; ko < 2; ++ko)
                            bfr[ni][ko] = *(const bf16x8*)(
                                sm + rb * 32768 + 16384 + rdB + ni * 1024 + ac[ko]);
                }

                // stage 1 half-tile per phase (schedule in header comment)
                if (p == 0)      { if (u + 1 < 16) STAGE_A(rb ^ 1, 1, u + 1); }
                else if (p == 1) { if (u + 2 < 16) STAGE_B(rb, 0, u + 2); }
                else if (p == 2) { if (u + 2 < 16) STAGE_B(rb, 1, u + 2); }
                else             { if (u + 2 < 16) STAGE_A(rb, 0, u + 2); }

                if (p == 0) asm volatile("s_waitcnt lgkmcnt(8)" ::: "memory");
                __builtin_amdgcn_s_barrier();
                asm volatile("s_waitcnt lgkmcnt(0)" ::: "memory");
                __builtin_amdgcn_sched_barrier(0);

                __builtin_amdgcn_s_setprio(1);
#pragma unroll
                for (int mi = 0; mi < 4; ++mi)
#pragma unroll
                    for (int ni = 0; ni < 2; ++ni)
#pragma unroll
                        for (int ko = 0; ko < 2; ++ko)
                            acc[p * 4 + mi][ni] = __builtin_amdgcn_mfma_f32_16x16x32_bf16(
                                af[mi][ko], bfr[ni][ko], acc[p * 4 + mi][ni], 0, 0, 0);
                __builtin_amdgcn_s_setprio(0);

                if (p == 3) {
                    // boundary: counted drain, never 0 until the tail
                    if (u <= 13)      asm volatile("s_waitcnt vmcnt(6)" ::: "memory");
                    else if (u == 14) asm volatile("s_waitcnt vmcnt(0)" ::: "memory");
                    if (u < 15) __builtin_amdgcn_s_barrier();
                } else {
                    __builtin_amdgcn_s_barrier();
                }
            }
        }
    }

    // ---- Epilogue: C/D layout col = lane&15 (tr), row = quad*4 + reg ----
    float bv[2]; int col[2];
#pragma unroll
    for (int ni = 0; ni < 2; ++ni) {
        col[ni] = n0 + wc * 32 + ni * 16 + tr;
        bv[ni]  = bias[col[ni]];
    }
#pragma unroll
    for (int f = 0; f < 16; ++f)
#pragma unroll
        for (int ni = 0; ni < 2; ++ni)
#pragma unroll
            for (int rr = 0; rr < 4; ++rr) {
                const int row = m0 + f * 16 + quad * 4 + rr;
                Y[(size_t)row * 1024 + col[ni]] =
                    __float2bfloat16(acc[f][ni][rr] + bv[ni]);
            }
}

// ---------------- norm: out = y / max(||y||,eps) * g * 32, 2 rows/block ----------------
__global__ __launch_bounds__(256)
void rmsnorm2(const __hip_bfloat16* __restrict__ y, const float* __restrict__ g,
              float* __restrict__ out) {
    const int wave = threadIdx.x >> 6;
    const int sub  = wave >> 1;
    const int t    = threadIdx.x & 127;
    const int row  = blockIdx.x * 2 + sub;
    const size_t base = (size_t)row * 1024 + t * 8;

    union { uint4 u; ushort s[8]; } U;
    U.u = *(const uint4*)(y + base);
    float v[8];
#pragma unroll
    for (int j = 0; j < 8; ++j)
        v[j] = __bfloat162float(*(const __hip_bfloat16*)&U.s[j]);

    float ss = 0.f;
#pragma unroll
    for (int j = 0; j < 8; ++j) ss += v[j] * v[j];
#pragma unroll
    for (int off = 32; off > 0; off >>= 1)
        ss += __shfl_down(ss, off, 64);

    __shared__ float wsum[4];
    if ((threadIdx.x & 63) == 0) wsum[wave] = ss;
    __syncthreads();
    const float total = wsum[sub * 2] + wsum[sub * 2 + 1];
    const float sc = 32.0f / fmaxf(sqrtf(total), 1e-12f);

    const float4 g0 = *(const float4*)(g + t * 8);
    const float4 g1 = *(const float4*)(g + t * 8 + 4);
    float4 o0, o1;
    o0.x = v[0] * sc * g0.x; o0.y = v[1] * sc * g0.y;
    o0.z = v[2] * sc * g0.z; o0.w = v[3] * sc * g0.w;
    o1.x = v[4] * sc * g1.x; o1.y = v[5] * sc * g1.y;
    o1.z = v[6] * sc * g1.z; o1.w = v[7] * sc * g1.w;
    *(float4*)(out + base)     = o0;
    *(float4*)(out + base + 4) = o1;
}

extern "C" void kernel_launch(void* const* d_in, const int* in_sizes, int n_in,
                              void* d_out, int out_size, void* d_ws, size_t ws_size,
                              hipStream_t stream) {
    const float* x     = (const float*)d_in[0];   // (16384, 1024)
    const float* w_qkv = (const float*)d_in[1];   // (1536, 1024)
    const float* w_out = (const float*)d_in[2];   // (1024, 512)
    const float* b_out = (const float*)d_in[3];   // (1024,)
    const float* g     = (const float*)d_in[4];   // (1, 1024)

    const int B = 16384, D = 1024, H = 512;
    const float* wv = w_qkv + (size_t)2 * H * D;  // v-rows: (512, 1024)

    char* ws = (char*)d_ws;
    size_t off = 0;
    __hip_bfloat16* weff_bf = (__hip_bfloat16*)(ws + off); off += (size_t)D * D * 2;  // 2 MB
    __hip_bfloat16* y_bf    = (__hip_bfloat16*)(ws + off); off += (size_t)B * D * 2;  // 33.6 MB
    __hip_bfloat16* x_bf    = (__hip_bfloat16*)(ws + off); off += (size_t)B * D * 2;  // 33.6 MB

    prep<<<256 + 2048, 256, 0, stream>>>(w_out, wv, weff_bf, x, x_bf);
    main_gemm<<<256, 512, 0, stream>>>(x_bf, weff_bf, b_out, y_bf);
    rmsnorm2<<<B / 2, 256, 0, stream>>>(y_bf, g, (float*)d_out);
}